// Round 20
// baseline (139.029 us; speedup 1.0000x reference)
//
#include <hip/hip_runtime.h>
#include <math.h>

typedef unsigned short ushort_t;
typedef unsigned short u16x8 __attribute__((ext_vector_type(8)));
typedef unsigned short u16x4 __attribute__((ext_vector_type(4)));
typedef short          s16x8 __attribute__((ext_vector_type(8)));
typedef float f32x4 __attribute__((ext_vector_type(4)));

#define THREADS 256
#define E_TILE  32
#define NBASIS  512
#define NBF     128
#define SBD     16
#define MBD     9
#define NTAP    9     // +-4 bins; dropped Gaussian mass ~4e-5 -> output err ~1e-5
#define XE_S    136   // ushort stride; 272B rows
#define H_S     40    // ushort stride; 80B rows
#define GG_S    136

// d_ws layout (ushort bf16)
#define WS_WET   0        // W_edge^T  [n=128][k=128]
#define WS_WG1T  16384    // W_g1^T    [q=32][k=128]
#define WS_WG2T  20480    // W_g2^T    [b*128+n=640][k=32]
#define WS_CGB   40960    // cgB [n=32][k=256]; n<16: cg_all, 16..24: cg_mid, 25..31: 0
#define WS_TOTAL 49152

// LDS offsets (float units) -- total 5344 floats = 20.9 KB; 6 blocks/CU = 125.3 KB
#define OFF_G    0      // 32*9 = 288 (dead after P1)
#define OFF_JLO  288    // 32 int
#define OFF_SRC  320    // 32 int
#define OFF_TGT  352    // 32 int  (region 0..384 dead after P1)
#define OFF_HS   0      // aliases G..TGT+pad: 640 floats = 32*40 ushort (h, written P3)
#define OFF_TPM  640    // 32*10 = 320
#define OFF_SUM  960    // 32
#define OFF_XE1  992    // 2176 floats = 32*136 ushort (xe1; ggS aliases after barrier 3)
#define OFF_GG   992
#define OFF_XE2  3168   // 2176
#define SMEM_FLOATS 5344

__device__ __forceinline__ float fsigmoid(float x){ return 1.0f/(1.0f + __expf(-x)); }
__device__ __forceinline__ float fsilu(float x){ return x/(1.0f + __expf(-x)); }

__device__ __forceinline__ ushort_t f2bf(float f){
  unsigned int u = __float_as_uint(f);
  u += 0x7FFFu + ((u >> 16) & 1u);
  return (ushort_t)(u >> 16);
}
__device__ __forceinline__ float bf2f(ushort_t h){
  return __uint_as_float(((unsigned int)h) << 16);
}
__device__ __forceinline__ void mfma_bf16(f32x4& d, u16x8 a, u16x8 b){
  d = __builtin_amdgcn_mfma_f32_16x16x32_bf16(
        __builtin_bit_cast(s16x8, a), __builtin_bit_cast(s16x8, b), d, 0, 0, 0);
}
// Non-temporal 16B store: output is write-once -> bypass L2 allocation.
__device__ __forceinline__ void nt_store4(float* p, f32x4 v){
  __builtin_nontemporal_store(v, (f32x4*)p);
}

__global__ void prep_weights_kernel(const float* __restrict__ We,
                                    const float* __restrict__ Wg1,
                                    const float* __restrict__ Wg2,
                                    const float* __restrict__ cgm,
                                    const float* __restrict__ cga,
                                    ushort_t* __restrict__ ws){
  int tid = blockIdx.x * 256 + threadIdx.x;
  if (tid < 16384) {                       // WeT[n][k] = We[k][n]
    int n = tid >> 7, k = tid & 127;
    ws[WS_WET + tid] = f2bf(We[k*128 + n]);
  } else if (tid < 20480) {                // Wg1T[q][k] = Wg1[k][q]
    int r = tid - 16384; int q = r >> 7, k = r & 127;
    ws[tid] = f2bf(Wg1[k*32 + q]);
  } else if (tid < 40960) {                // Wg2T[b*128+n][k] = Wg2[k][b*128+n]
    int r = tid - 20480; int bn = r >> 5, k = r & 31;
    ws[tid] = f2bf(Wg2[k*640 + bn]);
  } else if (tid < WS_TOTAL) {             // cgB[n][k], k = i*16+j
    int r = tid - WS_CGB; int n = r >> 8, k = r & 255;
    float v = (n < 16) ? cga[k*16 + n] : (n < 25) ? cgm[k*9 + (n-16)] : 0.0f;
    ws[tid] = f2bf(v);
  }
}

__global__ __launch_bounds__(THREADS, 6)
void edge_block_kernel(
    const float* __restrict__ edge_distance,
    const int*   __restrict__ source_element,
    const int*   __restrict__ target_element,
    const float* __restrict__ x_sph,
    const float* __restrict__ edge_sh,
    const float* __restrict__ W_dist,
    const float* __restrict__ b_dist,
    const float* __restrict__ src_emb,
    const float* __restrict__ tgt_emb,
    const float* __restrict__ b_edge,
    const float* __restrict__ b_g1,
    const float* __restrict__ b_g2,
    const float* __restrict__ W_path,
    const ushort_t* __restrict__ wT,
    float* __restrict__ out,
    int E)
{
  __shared__ float smem[SMEM_FLOATS];
  float* g_s   = smem + OFF_G;
  int*   jlo_s = (int*)(smem + OFF_JLO);
  int*   src_s = (int*)(smem + OFF_SRC);
  int*   tgt_s = (int*)(smem + OFF_TGT);
  float* tpm_s = smem + OFF_TPM;
  float* sum_s = smem + OFF_SUM;
  ushort_t* xe1 = (ushort_t*)(smem + OFF_XE1);
  ushort_t* xe2 = (ushort_t*)(smem + OFF_XE2);
  ushort_t* hS  = (ushort_t*)(smem + OFF_HS);   // aliases g/jlo/src/tgt (dead after P1)
  ushort_t* ggS = (ushort_t*)(smem + OFF_GG);   // aliases xe1 (dead after barrier 3)

  const int tid  = threadIdx.x;
  const int lane = tid & 63;
  const int wid  = tid >> 6;       // 0..3
  const int l16  = lane & 15;
  const int lq   = lane >> 4;      // 0..3
  const int m0   = (wid & 1) * 16;
  const int eb   = blockIdx.x * E_TILE;
  const int ne   = min(E_TILE, E - eb);
  const float INVD = (float)(NBASIS - 1) / 6.0f;   // 511/6

  // ---------------- P0: stage g/jlo/src/tgt ----------------
  if (tid < E_TILE) {
    bool v = (tid < ne);
    int ge = eb + min(tid, ne-1);
    src_s[tid] = v ? source_element[ge] : 0;
    tgt_s[tid] = v ? target_element[ge] : 0;
  }
  for (int idx = tid; idx < E_TILE*NTAP; idx += THREADS) {
    int e = idx / NTAP;
    int t = idx - e*NTAP;
    bool v = (e < ne);
    float d  = v ? edge_distance[eb + e] : 0.0f;
    float jd = d * INVD;
    int jlo  = (int)floorf(jd) - 4;
    int j    = jlo + t;
    float dj = jd - (float)j;
    float g  = (v && j >= 0 && j < NBASIS) ? __expf(-0.5f*dj*dj) : 0.0f;
    g_s[e*NTAP + t] = g;
    if (t == 0) jlo_s[e] = jlo;
  }
  __syncthreads();   // (1)

  // ---- P1: x_dist (9 taps) + emb + silu -> xe1 bf16 (2 edges x 2 pass) -
  {
    const int er = tid >> 5;       // 0..7 -> 4 edges each (2 per pass)
    const int cq = tid & 31;       // 0..31 -> 4 channels each
    const int c0 = cq << 2;
    const float4 bd = *(const float4*)(b_dist + c0);
    #pragma unroll 1
    for (int p=0;p<2;p++){
      const int e0 = (er << 2) + p*2;
      float acc[2][4];
      #pragma unroll
      for (int i=0;i<2;i++){ acc[i][0]=bd.x; acc[i][1]=bd.y; acc[i][2]=bd.z; acc[i][3]=bd.w; }
      for (int t=0; t<NTAP; t++){
        #pragma unroll
        for (int i=0;i<2;i++){
          int e = e0 + i;
          float g = g_s[e*NTAP + t];
          int j = jlo_s[e] + t;
          j = max(0, min(NBASIS-1, j));
          const float4 w = *(const float4*)(W_dist + j*NBF + c0);
          acc[i][0] += g*w.x; acc[i][1] += g*w.y; acc[i][2] += g*w.z; acc[i][3] += g*w.w;
        }
      }
      #pragma unroll
      for (int i=0;i<2;i++){
        int e = e0 + i;
        const float4 se = *(const float4*)(src_emb + src_s[e]*NBF + c0);
        const float4 te = *(const float4*)(tgt_emb + tgt_s[e]*NBF + c0);
        u16x4 v;
        v[0] = f2bf(fsilu(acc[i][0] + se.x + te.x));
        v[1] = f2bf(fsilu(acc[i][1] + se.y + te.y));
        v[2] = f2bf(fsilu(acc[i][2] + se.z + te.z));
        v[3] = f2bf(fsilu(acc[i][3] + se.w + te.w));
        *(u16x4*)(xe1 + e*XE_S + c0) = v;
      }
    }
  }
  __syncthreads();   // (2) publishes xe1

  // -------- Phase B: P4M (TP via MFMA, reg A-frags) + P2 (xe2 MFMA) ----
  {
    const int half = wid >> 1;          // 0: tp_all (n 0..15), 1: tp_mid
    const int nrow = half*16 + l16;
    const int row  = m0 + l16;
    const int iofs = lq >> 1;
    const int jb   = (lq & 1) * 8;
    // register diet: lane uses only xs[2k+iofs] -> load exactly those 8
    float xsv8[8], shv[8];
    if (row < ne){
      const int ge = eb + row;
      #pragma unroll
      for (int q=0;q<8;q++) xsv8[q] = x_sph[ge*SBD + 2*q + iofs];
      const float4 s0 = *(const float4*)(edge_sh + ge*SBD + jb);
      const float4 s1 = *(const float4*)(edge_sh + ge*SBD + jb + 4);
      shv[0]=s0.x; shv[1]=s0.y; shv[2]=s0.z; shv[3]=s0.w;
      shv[4]=s1.x; shv[5]=s1.y; shv[6]=s1.z; shv[7]=s1.w;
    } else {
      #pragma unroll
      for (int q=0;q<8;q++){ xsv8[q] = 0.0f; shv[q] = 0.0f; }
    }
    f32x4 tacc = (f32x4){0.f,0.f,0.f,0.f};
    #pragma unroll
    for (int kk=0; kk<8; kk++){
      const float x = xsv8[kk];
      u16x8 a;
      #pragma unroll
      for (int jj=0; jj<8; jj++) a[jj] = f2bf(x * shv[jj]);
      const u16x8 b = *(const u16x8*)(wT + WS_CGB + nrow*256 + kk*32 + lq*8);
      mfma_bf16(tacc, a, b);
    }
    if (half == 0){
      // in-register row-sum over 16 cols (lanes lq*16..lq*16+15 contiguous)
      #pragma unroll
      for (int j=0;j<4;j++){
        float t0 = __shfl(tacc[j], lq*16);      // col 0 value, pre-reduce
        float s = tacc[j];
        s += __shfl_xor(s,1); s += __shfl_xor(s,2);
        s += __shfl_xor(s,4); s += __shfl_xor(s,8);
        if (l16 == 0)
          sum_s[m0 + lq*4 + j] = fsigmoid(t0) * s;  // silu(t0)+sigmoid(t0)*sum(rest)
      }
    } else if (l16 < 9){
      #pragma unroll
      for (int j=0;j<4;j++)
        tpm_s[(m0 + lq*4 + j)*10 + l16] = tacc[j];
    }
  }
  const int nb = (wid >> 1) * 64;
  {
    u16x8 af[4];
    #pragma unroll
    for (int kk=0; kk<4; kk++)
      af[kk] = *(const u16x8*)(xe1 + (m0 + l16)*XE_S + kk*32 + lq*8);
    #pragma unroll
    for (int t=0;t<4;t++){
      f32x4 acc = (f32x4){0.f,0.f,0.f,0.f};
      #pragma unroll
      for (int kk=0; kk<4; kk++){
        const u16x8 b = *(const u16x8*)(wT + WS_WET + (nb + t*16 + l16)*128 + kk*32 + lq*8);
        mfma_bf16(acc, af[kk], b);
      }
      const int n = nb + t*16 + l16;
      const float be = b_edge[n];
      #pragma unroll
      for (int j=0;j<4;j++){
        const int m = m0 + lq*4 + j;
        xe2[m*XE_S + n] = f2bf(fsilu(acc[j] + be));
      }
    }
  }
  __syncthreads();   // (3) publishes xe2, tpm, sum (xe1 dead)

  // -------- Phase C: P3 (h MFMA) ---------------------------------------
  {
    const int n0 = (wid >> 1) * 16;   // 0 or 16
    f32x4 acc3 = (f32x4){0.f,0.f,0.f,0.f};
    #pragma unroll
    for (int kk=0; kk<4; kk++){
      const u16x8 a = *(const u16x8*)(xe2 + (m0 + l16)*XE_S + kk*32 + lq*8);
      const u16x8 b = *(const u16x8*)(wT + WS_WG1T + (n0 + l16)*128 + kk*32 + lq*8);
      mfma_bf16(acc3, a, b);
    }
    const float bg = b_g1[n0 + l16];
    #pragma unroll
    for (int j=0;j<4;j++){
      const int m = m0 + lq*4 + j;
      hS[m*H_S + n0 + l16] = f2bf(fmaxf(acc3[j] + bg, 0.0f));
    }
  }
  __syncthreads();   // (4) publishes h

  // -------- P5: gate0 = 1/(1+sum exp(zb-z0)) via MFMA -> ggS bf16 ------
  {
    const int cb = (wid >> 1) * 64;
    const u16x8 ah = *(const u16x8*)(hS + (m0 + l16)*H_S + lq*8);
    #pragma unroll
    for (int t=0;t<4;t++){
      const int c = cb + t*16 + l16;
      f32x4 z = (f32x4){0.f,0.f,0.f,0.f};
      {
        const u16x8 bw = *(const u16x8*)(wT + WS_WG2T + (size_t)c*32 + lq*8);
        mfma_bf16(z, ah, bw);
      }
      const float bg0 = b_g2[c];
      float z0[4], s4[4];
      #pragma unroll
      for (int j=0;j<4;j++){ z0[j] = z[j] + bg0; s4[j] = 1.0f; }
      #pragma unroll
      for (int b=1;b<5;b++){
        const u16x8 bw = *(const u16x8*)(wT + WS_WG2T + (size_t)(b*128 + c)*32 + lq*8);
        f32x4 zb = (f32x4){0.f,0.f,0.f,0.f};
        mfma_bf16(zb, ah, bw);
        const float bgb = b_g2[b*128 + c];
        #pragma unroll
        for (int j=0;j<4;j++) s4[j] += __expf(zb[j] + bgb - z0[j]);
      }
      #pragma unroll
      for (int j=0;j<4;j++){
        const int m = m0 + lq*4 + j;
        ggS[m*GG_S + c] = f2bf(__builtin_amdgcn_rcpf(s4[j]));
      }
    }
  }
  __syncthreads();   // (5) publishes ggS

  // ---- P6: assemble + non-temporal 16B stores; (4 edges)x(4 ch) -------
  {
    const int c0 = (tid & 31) << 2;
    const int mg = tid >> 5;           // 0..7
    const f32x4 wp0 = *(const f32x4*)(W_path + c0);
    const f32x4 wp1 = *(const f32x4*)(W_path + 128 + c0);
    const f32x4 wp2 = *(const f32x4*)(W_path + 256 + c0);
    #pragma unroll
    for (int mm=0; mm<4; mm++){
      const int m = mg*4 + mm;
      if (m < ne){
        const float sa = sum_s[m];
        const u16x4 xv = *(const u16x4*)(xe2 + m*XE_S + c0);
        const u16x4 gv = *(const u16x4*)(ggS + m*GG_S + c0);
        f32x4 base, gg, s0;
        const float tpm0 = tpm_s[m*10];
        #pragma unroll
        for (int j=0;j<4;j++){
          base[j] = bf2f(xv[j]) + sa;
          s0[j] = tpm0 * wp0[j];
          gg[j] = fsigmoid(s0[j]) * bf2f(gv[j]);
        }
        float* op = out + (size_t)(eb + m) * (MBD*NBF) + c0;
        f32x4 o;
        #pragma unroll
        for (int j=0;j<4;j++) o[j] = s0[j]*gg[j] + base[j];
        nt_store4(op, o);
        #pragma unroll
        for (int k=1;k<MBD;k++){
          const float tk = tpm_s[m*10 + k];      // per-k LDS read (reg diet)
          const f32x4 wv = (k < 4) ? wp1 : wp2;
          #pragma unroll
          for (int j=0;j<4;j++) o[j] = tk*wv[j]*gg[j] + base[j];
          nt_store4(op + k*NBF, o);
        }
      }
    }
  }
}

extern "C" void kernel_launch(void* const* d_in, const int* in_sizes, int n_in,
                              void* d_out, int out_size, void* d_ws, size_t ws_size,
                              hipStream_t stream) {
  const float* edge_distance  = (const float*)d_in[0];
  const int*   source_element = (const int*)  d_in[1];
  const int*   target_element = (const int*)  d_in[2];
  const float* x_sph   = (const float*)d_in[3];
  const float* edge_sh = (const float*)d_in[4];
  const float* W_dist  = (const float*)d_in[5];
  const float* b_dist  = (const float*)d_in[6];
  const float* src_emb = (const float*)d_in[7];
  const float* tgt_emb = (const float*)d_in[8];
  const float* W_edge  = (const float*)d_in[9];
  const float* b_edge  = (const float*)d_in[10];
  const float* W_g1    = (const float*)d_in[11];
  const float* b_g1    = (const float*)d_in[12];
  const float* W_g2    = (const float*)d_in[13];
  const float* b_g2    = (const float*)d_in[14];
  const float* cg_mid  = (const float*)d_in[15];
  const float* cg_all  = (const float*)d_in[16];
  const float* W_path  = (const float*)d_in[17];
  float* out = (float*)d_out;
  ushort_t* ws = (ushort_t*)d_ws;
  const int E = in_sizes[0];

  hipLaunchKernelGGL(prep_weights_kernel, dim3((WS_TOTAL + 255)/256), dim3(256), 0, stream,
                     W_edge, W_g1, W_g2, cg_mid, cg_all, ws);

  const int nblk = (E + E_TILE - 1) / E_TILE;
  hipLaunchKernelGGL(edge_block_kernel, dim3(nblk), dim3(THREADS), 0, stream,
                     edge_distance, source_element, target_element, x_sph, edge_sh,
                     W_dist, b_dist, src_emb, tgt_emb, b_edge,
                     b_g1, b_g2, W_path, ws, out, E);
}

// Round 21
// 121.980 us; speedup vs baseline: 1.1398x; 1.1398x over previous
//
#include <hip/hip_runtime.h>
#include <math.h>

typedef unsigned short ushort_t;
typedef unsigned short u16x8 __attribute__((ext_vector_type(8)));
typedef unsigned short u16x4 __attribute__((ext_vector_type(4)));
typedef short          s16x8 __attribute__((ext_vector_type(8)));
typedef float f32x4 __attribute__((ext_vector_type(4)));

#define THREADS 256
#define E_TILE  32
#define NBASIS  512
#define NBF     128
#define SBD     16
#define MBD     9
#define NTAP    9     // +-4 bins; dropped Gaussian mass ~4e-5 -> output err ~1e-5
#define XE_S    136   // ushort stride; 272B rows
#define H_S     40    // ushort stride; 80B rows
#define GG_S    136

// d_ws layout (ushort bf16)
#define WS_WET   0        // W_edge^T  [n=128][k=128]
#define WS_WG1T  16384    // W_g1^T    [q=32][k=128]
#define WS_WG2T  20480    // W_g2^T    [b*128+n=640][k=32]
#define WS_CGB   40960    // cgB [n=32][k=256]; n<16: cg_all, 16..24: cg_mid, 25..31: 0
#define WS_TOTAL 49152

// LDS offsets (float units) -- total 5344 floats = 20.9 KB; 5 blocks/CU = 104.4 KB
#define OFF_G    0      // 32*9 = 288 (dead after P1)
#define OFF_JLO  288    // 32 int
#define OFF_SRC  320    // 32 int
#define OFF_TGT  352    // 32 int  (region 0..384 dead after P1)
#define OFF_HS   0      // aliases G..TGT+pad: 640 floats = 32*40 ushort (h, written P3)
#define OFF_TPM  640    // 32*10 = 320
#define OFF_SUM  960    // 32
#define OFF_XE1  992    // 2176 floats = 32*136 ushort (xe1; ggS aliases after barrier 3)
#define OFF_GG   992
#define OFF_XE2  3168   // 2176
#define SMEM_FLOATS 5344

__device__ __forceinline__ float fsigmoid(float x){ return 1.0f/(1.0f + __expf(-x)); }
__device__ __forceinline__ float fsilu(float x){ return x/(1.0f + __expf(-x)); }

__device__ __forceinline__ ushort_t f2bf(float f){
  unsigned int u = __float_as_uint(f);
  u += 0x7FFFu + ((u >> 16) & 1u);
  return (ushort_t)(u >> 16);
}
__device__ __forceinline__ float bf2f(ushort_t h){
  return __uint_as_float(((unsigned int)h) << 16);
}
__device__ __forceinline__ void mfma_bf16(f32x4& d, u16x8 a, u16x8 b){
  d = __builtin_amdgcn_mfma_f32_16x16x32_bf16(
        __builtin_bit_cast(s16x8, a), __builtin_bit_cast(s16x8, b), d, 0, 0, 0);
}
// Non-temporal 16B store: output is write-once -> bypass L2 allocation.
__device__ __forceinline__ void nt_store4(float* p, f32x4 v){
  __builtin_nontemporal_store(v, (f32x4*)p);
}

__global__ void prep_weights_kernel(const float* __restrict__ We,
                                    const float* __restrict__ Wg1,
                                    const float* __restrict__ Wg2,
                                    const float* __restrict__ cgm,
                                    const float* __restrict__ cga,
                                    ushort_t* __restrict__ ws){
  int tid = blockIdx.x * 256 + threadIdx.x;
  if (tid < 16384) {                       // WeT[n][k] = We[k][n]
    int n = tid >> 7, k = tid & 127;
    ws[WS_WET + tid] = f2bf(We[k*128 + n]);
  } else if (tid < 20480) {                // Wg1T[q][k] = Wg1[k][q]
    int r = tid - 16384; int q = r >> 7, k = r & 127;
    ws[tid] = f2bf(Wg1[k*32 + q]);
  } else if (tid < 40960) {                // Wg2T[b*128+n][k] = Wg2[k][b*128+n]
    int r = tid - 20480; int bn = r >> 5, k = r & 31;
    ws[tid] = f2bf(Wg2[k*640 + bn]);
  } else if (tid < WS_TOTAL) {             // cgB[n][k], k = i*16+j
    int r = tid - WS_CGB; int n = r >> 8, k = r & 255;
    float v = (n < 16) ? cga[k*16 + n] : (n < 25) ? cgm[k*9 + (n-16)] : 0.0f;
    ws[tid] = f2bf(v);
  }
}

__global__ __launch_bounds__(THREADS, 5)
void edge_block_kernel(
    const float* __restrict__ edge_distance,
    const int*   __restrict__ source_element,
    const int*   __restrict__ target_element,
    const float* __restrict__ x_sph,
    const float* __restrict__ edge_sh,
    const float* __restrict__ W_dist,
    const float* __restrict__ b_dist,
    const float* __restrict__ src_emb,
    const float* __restrict__ tgt_emb,
    const float* __restrict__ b_edge,
    const float* __restrict__ b_g1,
    const float* __restrict__ b_g2,
    const float* __restrict__ W_path,
    const ushort_t* __restrict__ wT,
    float* __restrict__ out,
    int E)
{
  __shared__ float smem[SMEM_FLOATS];
  float* g_s   = smem + OFF_G;
  int*   jlo_s = (int*)(smem + OFF_JLO);
  int*   src_s = (int*)(smem + OFF_SRC);
  int*   tgt_s = (int*)(smem + OFF_TGT);
  float* tpm_s = smem + OFF_TPM;
  float* sum_s = smem + OFF_SUM;
  ushort_t* xe1 = (ushort_t*)(smem + OFF_XE1);
  ushort_t* xe2 = (ushort_t*)(smem + OFF_XE2);
  ushort_t* hS  = (ushort_t*)(smem + OFF_HS);   // aliases g/jlo/src/tgt (dead after P1)
  ushort_t* ggS = (ushort_t*)(smem + OFF_GG);   // aliases xe1 (dead after barrier 3)

  const int tid  = threadIdx.x;
  const int lane = tid & 63;
  const int wid  = tid >> 6;       // 0..3
  const int l16  = lane & 15;
  const int lq   = lane >> 4;      // 0..3
  const int m0   = (wid & 1) * 16;
  const int eb   = blockIdx.x * E_TILE;
  const int ne   = min(E_TILE, E - eb);
  const float INVD = (float)(NBASIS - 1) / 6.0f;   // 511/6

  // ---------------- P0: stage g/jlo/src/tgt ----------------
  if (tid < E_TILE) {
    bool v = (tid < ne);
    int ge = eb + min(tid, ne-1);
    src_s[tid] = v ? source_element[ge] : 0;
    tgt_s[tid] = v ? target_element[ge] : 0;
  }
  for (int idx = tid; idx < E_TILE*NTAP; idx += THREADS) {
    int e = idx / NTAP;
    int t = idx - e*NTAP;
    bool v = (e < ne);
    float d  = v ? edge_distance[eb + e] : 0.0f;
    float jd = d * INVD;
    int jlo  = (int)floorf(jd) - 4;
    int j    = jlo + t;
    float dj = jd - (float)j;
    float g  = (v && j >= 0 && j < NBASIS) ? __expf(-0.5f*dj*dj) : 0.0f;
    g_s[e*NTAP + t] = g;
    if (t == 0) jlo_s[e] = jlo;
  }
  __syncthreads();   // (1)

  // -------- P1: x_dist (9 taps) + emb + silu -> xe1 bf16 ---------------
  {
    const int er = tid >> 5;       // 0..7 -> 4 edges each
    const int cq = tid & 31;       // 0..31 -> 4 channels each
    const int e0 = er << 2;
    const int c0 = cq << 2;
    float acc[4][4];
    const float4 bd = *(const float4*)(b_dist + c0);
    #pragma unroll
    for (int i=0;i<4;i++){ acc[i][0]=bd.x; acc[i][1]=bd.y; acc[i][2]=bd.z; acc[i][3]=bd.w; }
    for (int t=0; t<NTAP; t++){
      #pragma unroll
      for (int i=0;i<4;i++){
        int e = e0 + i;
        float g = g_s[e*NTAP + t];
        int j = jlo_s[e] + t;
        j = max(0, min(NBASIS-1, j));
        const float4 w = *(const float4*)(W_dist + j*NBF + c0);
        acc[i][0] += g*w.x; acc[i][1] += g*w.y; acc[i][2] += g*w.z; acc[i][3] += g*w.w;
      }
    }
    #pragma unroll
    for (int i=0;i<4;i++){
      int e = e0 + i;
      const float4 se = *(const float4*)(src_emb + src_s[e]*NBF + c0);
      const float4 te = *(const float4*)(tgt_emb + tgt_s[e]*NBF + c0);
      u16x4 v;
      v[0] = f2bf(fsilu(acc[i][0] + se.x + te.x));
      v[1] = f2bf(fsilu(acc[i][1] + se.y + te.y));
      v[2] = f2bf(fsilu(acc[i][2] + se.z + te.z));
      v[3] = f2bf(fsilu(acc[i][3] + se.w + te.w));
      *(u16x4*)(xe1 + e*XE_S + c0) = v;
    }
  }
  __syncthreads();   // (2) publishes xe1

  // -------- Phase B: P4M (TP via MFMA, reg A-frags) + P2 (xe2 MFMA) ----
  {
    const int half = wid >> 1;          // 0: tp_all (n 0..15), 1: tp_mid
    const int nrow = half*16 + l16;
    const int row  = m0 + l16;
    const int iofs = lq >> 1;
    const int jb   = (lq & 1) * 8;
    // register diet: lane uses only xs[2k+iofs] -> load exactly those 8
    float xsv8[8], shv[8];
    if (row < ne){
      const int ge = eb + row;
      #pragma unroll
      for (int q=0;q<8;q++) xsv8[q] = x_sph[ge*SBD + 2*q + iofs];
      const float4 s0 = *(const float4*)(edge_sh + ge*SBD + jb);
      const float4 s1 = *(const float4*)(edge_sh + ge*SBD + jb + 4);
      shv[0]=s0.x; shv[1]=s0.y; shv[2]=s0.z; shv[3]=s0.w;
      shv[4]=s1.x; shv[5]=s1.y; shv[6]=s1.z; shv[7]=s1.w;
    } else {
      #pragma unroll
      for (int q=0;q<8;q++){ xsv8[q] = 0.0f; shv[q] = 0.0f; }
    }
    f32x4 tacc = (f32x4){0.f,0.f,0.f,0.f};
    #pragma unroll
    for (int kk=0; kk<8; kk++){
      const float x = xsv8[kk];
      u16x8 a;
      #pragma unroll
      for (int jj=0; jj<8; jj++) a[jj] = f2bf(x * shv[jj]);
      const u16x8 b = *(const u16x8*)(wT + WS_CGB + nrow*256 + kk*32 + lq*8);
      mfma_bf16(tacc, a, b);
    }
    if (half == 0){
      // in-register row-sum over 16 cols (lanes lq*16..lq*16+15 contiguous)
      #pragma unroll
      for (int j=0;j<4;j++){
        float t0 = __shfl(tacc[j], lq*16);      // col 0 value, pre-reduce
        float s = tacc[j];
        s += __shfl_xor(s,1); s += __shfl_xor(s,2);
        s += __shfl_xor(s,4); s += __shfl_xor(s,8);
        if (l16 == 0)
          sum_s[m0 + lq*4 + j] = fsigmoid(t0) * s;  // silu(t0)+sigmoid(t0)*sum(rest)
      }
    } else if (l16 < 9){
      #pragma unroll
      for (int j=0;j<4;j++)
        tpm_s[(m0 + lq*4 + j)*10 + l16] = tacc[j];
    }
  }
  const int nb = (wid >> 1) * 64;
  {
    u16x8 af[4];
    #pragma unroll
    for (int kk=0; kk<4; kk++)
      af[kk] = *(const u16x8*)(xe1 + (m0 + l16)*XE_S + kk*32 + lq*8);
    #pragma unroll
    for (int t=0;t<4;t++){
      f32x4 acc = (f32x4){0.f,0.f,0.f,0.f};
      #pragma unroll
      for (int kk=0; kk<4; kk++){
        const u16x8 b = *(const u16x8*)(wT + WS_WET + (nb + t*16 + l16)*128 + kk*32 + lq*8);
        mfma_bf16(acc, af[kk], b);
      }
      const int n = nb + t*16 + l16;
      const float be = b_edge[n];
      #pragma unroll
      for (int j=0;j<4;j++){
        const int m = m0 + lq*4 + j;
        xe2[m*XE_S + n] = f2bf(fsilu(acc[j] + be));
      }
    }
  }
  __syncthreads();   // (3) publishes xe2, tpm, sum (xe1 dead)

  // -------- Phase C: P3 (h MFMA) ---------------------------------------
  {
    const int n0 = (wid >> 1) * 16;   // 0 or 16
    f32x4 acc3 = (f32x4){0.f,0.f,0.f,0.f};
    #pragma unroll
    for (int kk=0; kk<4; kk++){
      const u16x8 a = *(const u16x8*)(xe2 + (m0 + l16)*XE_S + kk*32 + lq*8);
      const u16x8 b = *(const u16x8*)(wT + WS_WG1T + (n0 + l16)*128 + kk*32 + lq*8);
      mfma_bf16(acc3, a, b);
    }
    const float bg = b_g1[n0 + l16];
    #pragma unroll
    for (int j=0;j<4;j++){
      const int m = m0 + lq*4 + j;
      hS[m*H_S + n0 + l16] = f2bf(fmaxf(acc3[j] + bg, 0.0f));
    }
  }
  __syncthreads();   // (4) publishes h

  // -------- P5: gate0 = 1/(1+sum exp(zb-z0)) via MFMA -> ggS bf16 ------
  {
    const int cb = (wid >> 1) * 64;
    const u16x8 ah = *(const u16x8*)(hS + (m0 + l16)*H_S + lq*8);
    #pragma unroll
    for (int t=0;t<4;t++){
      const int c = cb + t*16 + l16;
      f32x4 z = (f32x4){0.f,0.f,0.f,0.f};
      {
        const u16x8 bw = *(const u16x8*)(wT + WS_WG2T + (size_t)c*32 + lq*8);
        mfma_bf16(z, ah, bw);
      }
      const float bg0 = b_g2[c];
      float z0[4], s4[4];
      #pragma unroll
      for (int j=0;j<4;j++){ z0[j] = z[j] + bg0; s4[j] = 1.0f; }
      #pragma unroll
      for (int b=1;b<5;b++){
        const u16x8 bw = *(const u16x8*)(wT + WS_WG2T + (size_t)(b*128 + c)*32 + lq*8);
        f32x4 zb = (f32x4){0.f,0.f,0.f,0.f};
        mfma_bf16(zb, ah, bw);
        const float bgb = b_g2[b*128 + c];
        #pragma unroll
        for (int j=0;j<4;j++) s4[j] += __expf(zb[j] + bgb - z0[j]);
      }
      #pragma unroll
      for (int j=0;j<4;j++){
        const int m = m0 + lq*4 + j;
        ggS[m*GG_S + c] = f2bf(__builtin_amdgcn_rcpf(s4[j]));
      }
    }
  }
  __syncthreads();   // (5) publishes ggS

  // ---- P6: assemble + non-temporal 16B stores; (4 edges)x(4 ch) -------
  {
    const int c0 = (tid & 31) << 2;
    const int mg = tid >> 5;           // 0..7
    const f32x4 wp0 = *(const f32x4*)(W_path + c0);
    const f32x4 wp1 = *(const f32x4*)(W_path + 128 + c0);
    const f32x4 wp2 = *(const f32x4*)(W_path + 256 + c0);
    #pragma unroll
    for (int mm=0; mm<4; mm++){
      const int m = mg*4 + mm;
      if (m < ne){
        const float sa = sum_s[m];
        const u16x4 xv = *(const u16x4*)(xe2 + m*XE_S + c0);
        const u16x4 gv = *(const u16x4*)(ggS + m*GG_S + c0);
        float tpmv[9];
        #pragma unroll
        for (int k=0;k<MBD;k++) tpmv[k] = tpm_s[m*10 + k];
        f32x4 base, gg, s0;
        #pragma unroll
        for (int j=0;j<4;j++){
          base[j] = bf2f(xv[j]) + sa;
          s0[j] = tpmv[0] * wp0[j];
          gg[j] = fsigmoid(s0[j]) * bf2f(gv[j]);
        }
        float* op = out + (size_t)(eb + m) * (MBD*NBF) + c0;
        f32x4 o;
        #pragma unroll
        for (int j=0;j<4;j++) o[j] = s0[j]*gg[j] + base[j];
        nt_store4(op, o);
        #pragma unroll
        for (int k=1;k<MBD;k++){
          const f32x4 wv = (k < 4) ? wp1 : wp2;
          #pragma unroll
          for (int j=0;j<4;j++) o[j] = tpmv[k]*wv[j]*gg[j] + base[j];
          nt_store4(op + k*NBF, o);
        }
      }
    }
  }
}

extern "C" void kernel_launch(void* const* d_in, const int* in_sizes, int n_in,
                              void* d_out, int out_size, void* d_ws, size_t ws_size,
                              hipStream_t stream) {
  const float* edge_distance  = (const float*)d_in[0];
  const int*   source_element = (const int*)  d_in[1];
  const int*   target_element = (const int*)  d_in[2];
  const float* x_sph   = (const float*)d_in[3];
  const float* edge_sh = (const float*)d_in[4];
  const float* W_dist  = (const float*)d_in[5];
  const float* b_dist  = (const float*)d_in[6];
  const float* src_emb = (const float*)d_in[7];
  const float* tgt_emb = (const float*)d_in[8];
  const float* W_edge  = (const float*)d_in[9];
  const float* b_edge  = (const float*)d_in[10];
  const float* W_g1    = (const float*)d_in[11];
  const float* b_g1    = (const float*)d_in[12];
  const float* W_g2    = (const float*)d_in[13];
  const float* b_g2    = (const float*)d_in[14];
  const float* cg_mid  = (const float*)d_in[15];
  const float* cg_all  = (const float*)d_in[16];
  const float* W_path  = (const float*)d_in[17];
  float* out = (float*)d_out;
  ushort_t* ws = (ushort_t*)d_ws;
  const int E = in_sizes[0];

  hipLaunchKernelGGL(prep_weights_kernel, dim3((WS_TOTAL + 255)/256), dim3(256), 0, stream,
                     W_edge, W_g1, W_g2, cg_mid, cg_all, ws);

  const int nblk = (E + E_TILE - 1) / E_TILE;
  hipLaunchKernelGGL(edge_block_kernel, dim3(nblk), dim3(THREADS), 0, stream,
                     edge_distance, source_element, target_element, x_sph, edge_sh,
                     W_dist, b_dist, src_emb, tgt_emb, b_edge,
                     b_g1, b_g2, W_path, ws, out, E);
}